// Round 4
// baseline (364.646 us; speedup 1.0000x reference)
//
#include <hip/hip_runtime.h>

#define NBINS 10
#define ROWW  21         // dwords per thread-private LDS row: 10 x (prob,cnt) + 1 pad.
                         // ODD stride: bank(prob) = (21*lane + 2b) % 32, odd multiplier is
                         // bijective in lane mod 32 -> atomics spread over all 32 banks.
                         // 256*21*4 = 21504 B -> 7 blocks/CU.
#define PART_STRIDE 32   // per-block partial row stride (padded from 30)

// Round 4: thread-private LDS rows + NO-RETURN LDS atomics (ds_add_f32 /
// ds_add_u32 fire-and-forget). No RMW dependency chain, no per-element
// waitcnt -- DS pipe does the add internally. count low16 / tp high16
// packed: <=76 elems/thread at grid=1792, exact.
__global__ __launch_bounds__(256) void calib_hist(
    const float* __restrict__ outputs,
    const float* __restrict__ labels,
    float* __restrict__ partials,
    long n)
{
    __shared__ __align__(16) unsigned int s_hist[256 * ROWW];

    const int tid = threadIdx.x;
    for (int j = tid; j < 256 * ROWW; j += 256) s_hist[j] = 0u;
    __syncthreads();

    const float low0 = -1e-6f;
    const float step = (1.0f - low0) / 10.0f;   // fp32 linspace delta (const-folded)
    float*        rowf = (float*)&s_hist[tid * ROWW];
    unsigned int* rowu = &s_hist[tid * ROWW];

    const long total4 = n >> 2;
    const float4* o4 = (const float4*)outputs;
    const float4* l4 = (const float4*)labels;
    const long gid = (long)blockIdx.x * blockDim.x + tid;
    const long gsz = (long)gridDim.x * blockDim.x;

    for (long i = gid; i < total4; i += gsz) {
        float4 o = o4[i];
        float4 l = l4[i];
        float xs[4] = {o.x, o.y, o.z, o.w};
        float ys[4] = {l.x, l.y, l.z, l.w};
#pragma unroll
        for (int k = 0; k < 4; ++k) {
            float x = xs[k];
            bool valid = (x > low0) & (x <= 1.0f);
            int e = (int)(x * 10.0f);
            e = e < 0 ? 0 : (e > 9 ? 9 : e);
            float fe  = (float)e;
            float hb0 = fmaf(fe,        step, low0);   // high[e-1]
            float hb1 = fmaf(fe + 1.0f, step, low0);   // high[e]
            int b = e + ((x > hb1) ? 1 : 0) - (((e > 0) & (x <= hb0)) ? 1 : 0);
            b = b < 0 ? 0 : (b > 9 ? 9 : b);
            float        px = valid ? x : 0.0f;
            unsigned int pc = valid ? ((ys[k] > 0.5f) ? 0x10001u : 1u) : 0u;
            atomicAdd(&rowf[2 * b], px);       // ds_add_f32, no return
            atomicAdd(&rowu[2 * b + 1], pc);   // ds_add_u32, no return
        }
    }

    // scalar tail for n % 4 != 0 (not hit for this shape)
    const long tail0 = total4 << 2;
    for (long j = tail0 + gid; j < n; j += gsz) {
        float x = outputs[j];
        float y = labels [j];
        bool valid = (x > low0) & (x <= 1.0f);
        int e = (int)(x * 10.0f);
        e = e < 0 ? 0 : (e > 9 ? 9 : e);
        float fe  = (float)e;
        float hb0 = fmaf(fe,        step, low0);
        float hb1 = fmaf(fe + 1.0f, step, low0);
        int b = e + ((x > hb1) ? 1 : 0) - (((e > 0) & (x <= hb0)) ? 1 : 0);
        b = b < 0 ? 0 : (b > 9 ? 9 : b);
        float        px = valid ? x : 0.0f;
        unsigned int pc = valid ? ((y > 0.5f) ? 0x10001u : 1u) : 0u;
        atomicAdd(&rowf[2 * b], px);
        atomicAdd(&rowu[2 * b + 1], pc);
    }

    __syncthreads();

    // Block reduce: 240 threads, slot = tid%30 (0-9 prob, 10-19 tp, 20-29 count),
    // chunk = tid/30 sums 32 rows; partial stashed in row pad word (offset 20)
    // of row (chunk*30+slot) -- pad unused by histogram, no extra LDS.
    if (tid < 240) {
        int slot  = tid % 30;
        int chunk = tid / 30;
        int b = slot % NBINS;
        float acc = 0.0f;
        int r0 = chunk * 32;
        for (int r = r0; r < r0 + 32; ++r) {
            unsigned int base = (unsigned int)r * ROWW + 2 * b;
            if (slot < NBINS) {
                acc += __uint_as_float(s_hist[base]);
            } else {
                unsigned int c = s_hist[base + 1];
                acc += (slot < 2 * NBINS) ? (float)(c >> 16) : (float)(c & 0xFFFFu);
            }
        }
        ((float*)s_hist)[(unsigned int)(chunk * 30 + slot) * ROWW + 20] = acc;
    }
    __syncthreads();
    if (tid < 3 * NBINS) {
        float s = 0.0f;
#pragma unroll
        for (int c = 0; c < 8; ++c)
            s += ((float*)s_hist)[(unsigned int)(c * 30 + tid) * ROWW + 20];
        partials[(long)blockIdx.x * PART_STRIDE + tid] = s;
    }
}

// Kernel 2: one block per output slot; double-precision accumulate of partials.
__global__ __launch_bounds__(256) void calib_reduce(
    const float* __restrict__ partials, float* __restrict__ out, int nrows)
{
    const int s   = blockIdx.x;    // 0..29
    const int tid = threadIdx.x;
    double acc = 0.0;
    for (int r = tid; r < nrows; r += 256)
        acc += (double)partials[(long)r * PART_STRIDE + s];
#pragma unroll
    for (int off = 32; off > 0; off >>= 1)
        acc += __shfl_down(acc, off, 64);
    __shared__ double wsum[4];
    if ((tid & 63) == 0) wsum[tid >> 6] = acc;
    __syncthreads();
    if (tid == 0) out[s] = (float)(wsum[0] + wsum[1] + wsum[2] + wsum[3]);
}

extern "C" void kernel_launch(void* const* d_in, const int* in_sizes, int n_in,
                              void* d_out, int out_size, void* d_ws, size_t ws_size,
                              hipStream_t stream) {
    const float* outputs = (const float*)d_in[0];
    const float* labels  = (const float*)d_in[1];
    float* out = (float*)d_out;
    long n = (long)in_sizes[0];

    // 21504 B LDS/block -> 7 blocks/CU; grid = 7*256 so all blocks co-resident,
    // <=76 elems/thread keeps 16-bit count packing exact.
    int nblocks = 1792;
    size_t need = (size_t)nblocks * PART_STRIDE * sizeof(float);
    if (ws_size < need) {
        nblocks = (int)(ws_size / (PART_STRIDE * sizeof(float)));
        if (nblocks < 1) nblocks = 1;
    }
    float* partials = (float*)d_ws;

    calib_hist  <<<nblocks, 256, 0, stream>>>(outputs, labels, partials, n);
    calib_reduce<<<3 * NBINS, 256, 0, stream>>>(partials, out, nblocks);
}

// Round 5
// 287.745 us; speedup vs baseline: 1.2673x; 1.2673x over previous
//
#include <hip/hip_runtime.h>

#define NBINS 10
#define ROWW  19         // LDS row stride (dwords): 10 prob + 8 packed cnt/tp + 1 pad (odd stride)
#define PART_STRIDE 32   // per-block partial row stride (padded from 30)

// Round 5: pure-register accumulation (no per-element LDS: rounds 3/4 proved
// DS RMW/atomics cost >=1.7cyc/lane-op or chain latency).
//  - prob: 10 fp32 regs, 10-way predicated add chain (cmp+cndmask+add).
//  - count/tp: 64-bit shift-packed accumulators, 6-bit field per bin
//    (exact: <=32 elems between flushes), flushed into 12-bit-field pairs
//    (capacity 4095/bin/thread -> correct for any grid >= n/(256*4095) blocks).
//  ~55 VALU lane-ops/elem vs Round 2's measured ~120.
__global__ __launch_bounds__(256) void calib_hist(
    const float* __restrict__ outputs,
    const float* __restrict__ labels,
    float* __restrict__ partials,
    long n)
{
    __shared__ unsigned int s_lane[256 * ROWW];   // 19456 B
    __shared__ float        s_red[240];           // chunk partials (8 x 30)

    const int tid = threadIdx.x;
    const float low0 = -1e-6f;
    const float step = (1.0f - low0) / 10.0f;     // fp32 linspace delta (const-folded)

    float prob[NBINS];
#pragma unroll
    for (int b = 0; b < NBINS; ++b) prob[b] = 0.0f;
    unsigned long long cnt64 = 0ull, tp64 = 0ull;            // 6-bit fields, bins 0..9
    unsigned long long cntA = 0ull, cntB = 0ull;             // 12-bit fields, bins 0-4 / 5-9
    unsigned long long tpA  = 0ull, tpB  = 0ull;

    auto body = [&](float x, float y) {
        bool valid = (x > low0) & (x <= 1.0f);
        int e = (int)(x * 10.0f);
        e = e < 0 ? 0 : (e > 9 ? 9 : e);
        float fe  = (float)e;
        float hb0 = fmaf(fe,        step, low0);   // high[e-1]
        float hb1 = fmaf(fe + 1.0f, step, low0);   // high[e]
        int b = e + ((x > hb1) ? 1 : 0) - (((e > 0) & (x <= hb0)) ? 1 : 0);
        // b in [0,10]; b==10 only for invalid (x>1) -> inc=0, spill bits 60-63 unused.
        float px = valid ? x : 0.0f;
        unsigned long long one = (unsigned long long)(valid ? 1u : 0u) << (b * 6);
        cnt64 += one;
        tp64  += (y > 0.5f) ? one : 0ull;
#pragma unroll
        for (int bb = 0; bb < NBINS; ++bb)
            prob[bb] += (b == bb) ? px : 0.0f;
    };

    auto flush = [&]() {
#pragma unroll
        for (int f = 0; f < 5; ++f) {
            cntA += ((cnt64 >> (6 * f))      & 63ull) << (12 * f);
            cntB += ((cnt64 >> (6 * f + 30)) & 63ull) << (12 * f);
            tpA  += ((tp64  >> (6 * f))      & 63ull) << (12 * f);
            tpB  += ((tp64  >> (6 * f + 30)) & 63ull) << (12 * f);
        }
        cnt64 = 0ull; tp64 = 0ull;
    };

    const long total4 = n >> 2;
    const float4* o4 = (const float4*)outputs;
    const float4* l4 = (const float4*)labels;
    const long gid = (long)blockIdx.x * 256 + tid;
    const long gsz = (long)gridDim.x * 256;

    int since = 0;
    long j = gid;
    // unroll x2: 4 independent float4 loads in flight per iteration (MLP)
    for (; j + gsz < total4; j += 2 * gsz) {
        float4 oa = o4[j];       float4 la = l4[j];
        float4 ob = o4[j + gsz]; float4 lb = l4[j + gsz];
        body(oa.x, la.x); body(oa.y, la.y); body(oa.z, la.z); body(oa.w, la.w);
        body(ob.x, lb.x); body(ob.y, lb.y); body(ob.z, lb.z); body(ob.w, lb.w);
        if (++since == 4) { flush(); since = 0; }   // <=32 elems per 6-bit window
    }
    if (j < total4) {            // at most one leftover float4 per thread
        float4 oa = o4[j]; float4 la = l4[j];
        body(oa.x, la.x); body(oa.y, la.y); body(oa.z, la.z); body(oa.w, la.w);
    }
    // scalar tail for n % 4 != 0 (not hit for this shape)
    const long tail0 = total4 << 2;
    for (long t = tail0 + gid; t < n; t += gsz)
        body(outputs[t], labels[t]);
    flush();

    // ---- epilogue: one LDS dump per lane, 2-level block reduce ----
    unsigned int* row = &s_lane[tid * ROWW];
#pragma unroll
    for (int b = 0; b < NBINS; ++b) row[b] = __float_as_uint(prob[b]);
    row[10] = (unsigned)cntA; row[11] = (unsigned)(cntA >> 32);
    row[12] = (unsigned)cntB; row[13] = (unsigned)(cntB >> 32);
    row[14] = (unsigned)tpA;  row[15] = (unsigned)(tpA  >> 32);
    row[16] = (unsigned)tpB;  row[17] = (unsigned)(tpB  >> 32);
    __syncthreads();

    // slots: 0-9 prob, 10-19 tp, 20-29 count (matches d_out layout)
    if (tid < 240) {
        int chunk = tid / 30, slot = tid % 30;
        int r0 = chunk * 32;
        float acc = 0.0f;
        if (slot < NBINS) {
            for (int r = r0; r < r0 + 32; ++r)
                acc += __uint_as_float(s_lane[r * ROWW + slot]);
        } else {
            int b   = slot - ((slot < 20) ? 10 : 20);
            int off = ((slot < 20) ? 14 : 10) + ((b < 5) ? 0 : 2);  // tp at 14/16, cnt at 10/12
            int sh  = 12 * ((b < 5) ? b : b - 5);
            for (int r = r0; r < r0 + 32; ++r) {
                unsigned long long w =
                    ((unsigned long long)s_lane[r * ROWW + off + 1] << 32) |
                     (unsigned long long)s_lane[r * ROWW + off];
                acc += (float)((unsigned)((w >> sh) & 4095ull));
            }
        }
        s_red[chunk * 30 + slot] = acc;
    }
    __syncthreads();
    if (tid < 3 * NBINS) {
        float s = 0.0f;
#pragma unroll
        for (int c = 0; c < 8; ++c) s += s_red[c * 30 + tid];
        partials[(long)blockIdx.x * PART_STRIDE + tid] = s;
    }
}

// Kernel 2: one block per output slot; double-precision accumulate of partials.
__global__ __launch_bounds__(256) void calib_reduce(
    const float* __restrict__ partials, float* __restrict__ out, int nrows)
{
    const int s   = blockIdx.x;    // 0..29
    const int tid = threadIdx.x;
    double acc = 0.0;
    for (int r = tid; r < nrows; r += 256)
        acc += (double)partials[(long)r * PART_STRIDE + s];
#pragma unroll
    for (int off = 32; off > 0; off >>= 1)
        acc += __shfl_down(acc, off, 64);
    __shared__ double wsum[4];
    if ((tid & 63) == 0) wsum[tid >> 6] = acc;
    __syncthreads();
    if (tid == 0) out[s] = (float)(wsum[0] + wsum[1] + wsum[2] + wsum[3]);
}

extern "C" void kernel_launch(void* const* d_in, const int* in_sizes, int n_in,
                              void* d_out, int out_size, void* d_ws, size_t ws_size,
                              hipStream_t stream) {
    const float* outputs = (const float*)d_in[0];
    const float* labels  = (const float*)d_in[1];
    float* out = (float*)d_out;
    long n = (long)in_sizes[0];

    // 2048 blocks = 8/CU (ws-proven 256 KB partials); 64 elems/thread.
    // Packed-field safety needs elems/thread <= 4095 -> nblocks >= n/(256*4095).
    int nblocks = 2048;
    size_t need = (size_t)nblocks * PART_STRIDE * sizeof(float);
    if (ws_size < need) {
        nblocks = (int)(ws_size / (PART_STRIDE * sizeof(float)));
        if (nblocks < 1) nblocks = 1;
    }
    float* partials = (float*)d_ws;

    calib_hist  <<<nblocks, 256, 0, stream>>>(outputs, labels, partials, n);
    calib_reduce<<<3 * NBINS, 256, 0, stream>>>(partials, out, nblocks);
}